// Round 3
// baseline (12743.233 us; speedup 1.0000x reference)
//
#include <hip/hip_runtime.h>
#include <hip/hip_bf16.h>

#define NB      8192
#define NHID    512
#define NN      50000
#define NC      40
#define KSEL    41        // K+1
#define NCHUNK  4
#define CHUNK   12500
#define NTILES4 391       // ceil(12500/32)
#define NTILES1 1563      // ceil(50000/32)
#define EPS_F   1e-5f

typedef __attribute__((ext_vector_type(8))) short  short8;
typedef __attribute__((ext_vector_type(4))) float  floatx4;

// ---- big-ws layout (path A), byte offsets ----
#define OFF_INVN 0u          // 50000 f32
#define OFF_LSE  200704u     // 8192 f32
#define OFF_PVAL 233472u     // 8192*4*41 f32
#define OFF_PIDX 5607424u    // 8192*4*41 i32
#define OFF_ACC  10981376u   // [0]=entropy sum, [1]=logp sum, [2..41]=class sums
#define WS_NEED  10981568u

// f32 -> bf16 RNE (no NaN handling needed; inputs are finite)
__device__ __forceinline__ short f2b(float f) {
    union { float f; unsigned u; } x; x.f = f;
    unsigned r = x.u + 0x7fffu + ((x.u >> 16) & 1u);
    return (short)(r >> 16);
}

__global__ void k_init(float* __restrict__ acc) {
    int t = threadIdx.x;
    if (t < 48) acc[t] = 0.f;
}

// softmax stats on cls (f32): entropy terms, per-class sums, optional per-row lse
__global__ __launch_bounds__(256) void k_cls(const float* __restrict__ cls,
                                             float* __restrict__ lse,
                                             float* __restrict__ acc) {
    __shared__ float cacc[NC];
    __shared__ float entacc;
    int t = threadIdx.x;
    if (t == 0) entacc = 0.f;
    if (t < NC) cacc[t] = 0.f;
    __syncthreads();
    int row = blockIdx.x * 256 + t;
    float x[NC];
#pragma unroll
    for (int c = 0; c < NC; c++) x[c] = cls[row * NC + c];
    float m = x[0];
#pragma unroll
    for (int c = 1; c < NC; c++) m = fmaxf(m, x[c]);
    float S = 0.f;
#pragma unroll
    for (int c = 0; c < NC; c++) { float e = expf(x[c] - m); x[c] = e; S += e; }
    if (lse) lse[row] = m + logf(S);
    float inv = 1.f / S, ent = 0.f;
#pragma unroll
    for (int c = 0; c < NC; c++) {
        float p = x[c] * inv;
        ent += p * logf(p + EPS_F);
        atomicAdd(&cacc[c], p);
    }
    for (int off = 32; off; off >>= 1) ent += __shfl_xor(ent, off);
    if ((t & 63) == 0) atomicAdd(&entacc, ent);
    __syncthreads();
    if (t == 0) atomicAdd(&acc[0], entacc);
    if (t < NC) atomicAdd(&acc[2 + t], cacc[t]);
}

__global__ void k_final(const float* __restrict__ acc, float* __restrict__ out) {
    if (threadIdx.x == 0) {
        float ent = -acc[0] / (float)NB;
        float cl  = -acc[1] / (float)NB;
        float div = 0.f;
        for (int c = 0; c < NC; c++) {
            float msm = acc[2 + c] / (float)NB;
            div += msm * logf(msm + EPS_F);
        }
        out[0] = ent + div + cl;
    }
}

// ======================= PATH A (ws >= 11MB) =======================

// 1/||mem_fea_row||, one wave per row (f32 input, exact like reference)
__global__ __launch_bounds__(256) void k_invnorm(const float* __restrict__ mem,
                                                 float* __restrict__ invn) {
    int w = threadIdx.x >> 6, lane = threadIdx.x & 63;
    int row = blockIdx.x * 4 + w;
    const float* p = mem + (size_t)row * NHID + lane * 8;
    float4 a = *(const float4*)p;
    float4 b = *(const float4*)(p + 4);
    float s = a.x * a.x + a.y * a.y + a.z * a.z + a.w * a.w
            + b.x * b.x + b.y * b.y + b.z * b.z + b.w * b.w;
    for (int off = 32; off; off >>= 1) s += __shfl_xor(s, off);
    if (lane == 0) invn[row] = 1.f / fmaxf(sqrtf(s), 1e-12f);
}

// GEMM (f32 in, bf16 MFMA on raw dots) + streaming exact top-41 per row per chunk.
// Block: 256 thr (4 waves), M=64 feat rows, N-tile=32 mem rows, K=512 full.
__global__ __launch_bounds__(256, 2) void k_gemm_topk4(
        const float* __restrict__ feat,
        const float* __restrict__ mem,
        const float* __restrict__ invn,
        float* __restrict__ pval, int* __restrict__ pidx) {
    __shared__ __align__(16) unsigned short Bbuf[32][520];
    __shared__ float simbuf[64][33];
    __shared__ float lvals[64][KSEL];
    __shared__ int   lidx[64][KSEL];
    __shared__ float invs[32];

    const int tid  = threadIdx.x;
    const int lane = tid & 63;
    const int w    = tid >> 6;
    const int quad = lane >> 4;
    const int l16  = lane & 15;
    const int mbase  = blockIdx.x * 64;
    const int chunk  = blockIdx.y;
    const int nstart = chunk * CHUNK;

    // A fragments (convert once): row = mbase + w*16 + l16, k = s*32 + quad*8 .. +8
    short8 afrag[16];
    {
        const float* ar = feat + (size_t)(mbase + w * 16 + l16) * NHID + quad * 8;
#pragma unroll
        for (int s = 0; s < 16; s++) {
            float4 a = *(const float4*)(ar + s * 32);
            float4 b = *(const float4*)(ar + s * 32 + 4);
            short8 f;
            f[0] = f2b(a.x); f[1] = f2b(a.y); f[2] = f2b(a.z); f[3] = f2b(a.w);
            f[4] = f2b(b.x); f[5] = f2b(b.y); f[6] = f2b(b.z); f[7] = f2b(b.w);
            afrag[s] = f;
        }
    }

    if (tid < 64) {
        for (int i = 0; i < KSEL; i++) { lvals[tid][i] = -INFINITY; lidx[tid][i] = 0x7fffffff; }
    }
    // scan owners: 16 per wave — thread t with ((t>>4)&3)==0 owns row (t>>6)*16 + (t&15)
    const bool owner = ((tid >> 4) & 3) == 0;
    const int  orow  = (tid >> 6) * 16 + (tid & 15);
    float minv = -INFINITY; int mini = 0x7fffffff; int minp = 0;

    for (int t = 0; t < NTILES4; t++) {
        __syncthreads();
        const int rbase = nstart + t * 32;
        // stage B: 32 rows x 512 (f32 global -> bf16 LDS)
#pragma unroll
        for (int s = 0; s < 8; s++) {
            int id = tid + s * 256;
            int rl = id >> 6, ck = id & 63;
            int rg = rbase + rl; if (rg > NN - 1) rg = NN - 1;
            const float* src = mem + (size_t)rg * NHID + ck * 8;
            float4 a = *(const float4*)src;
            float4 b = *(const float4*)(src + 4);
            short8 f;
            f[0] = f2b(a.x); f[1] = f2b(a.y); f[2] = f2b(a.z); f[3] = f2b(a.w);
            f[4] = f2b(b.x); f[5] = f2b(b.y); f[6] = f2b(b.z); f[7] = f2b(b.w);
            *(short8*)&Bbuf[rl][ck * 8] = f;
        }
        if (tid < 32) { int rg = rbase + tid; invs[tid] = invn[rg > NN - 1 ? NN - 1 : rg]; }
        __syncthreads();

        floatx4 acc0 = {0.f, 0.f, 0.f, 0.f}, acc1 = {0.f, 0.f, 0.f, 0.f};
#pragma unroll
        for (int s = 0; s < 16; s++) {
            short8 b0 = *(const short8*)&Bbuf[l16][s * 32 + quad * 8];
            short8 b1 = *(const short8*)&Bbuf[16 + l16][s * 32 + quad * 8];
            acc0 = __builtin_amdgcn_mfma_f32_16x16x32_bf16(afrag[s], b0, acc0, 0, 0, 0);
            acc1 = __builtin_amdgcn_mfma_f32_16x16x32_bf16(afrag[s], b1, acc1, 0, 0, 0);
        }
#pragma unroll
        for (int r = 0; r < 4; r++) {           // C: col=lane&15, row=quad*4+reg
            simbuf[w * 16 + quad * 4 + r][l16]      = acc0[r];
            simbuf[w * 16 + quad * 4 + r][16 + l16] = acc1[r];
        }
        __syncthreads();

        if (owner) {
            int lim = CHUNK - t * 32; if (lim > 32) lim = 32;
            for (int c = 0; c < lim; c++) {
                float v = simbuf[orow][c] * invs[c];
                if (v > minv) {                  // ascending stream: ties keep smaller idx
                    lvals[orow][minp] = v; lidx[orow][minp] = rbase + c;
                    minv = INFINITY; mini = -1;
                    for (int i = 0; i < KSEL; i++) {
                        float lv = lvals[orow][i]; int li = lidx[orow][i];
                        if (lv < minv || (lv == minv && li > mini)) { minv = lv; mini = li; minp = i; }
                    }
                }
            }
        }
    }
    if (tid < 64) {
        int g = mbase + tid;
        int base = (g * NCHUNK + chunk) * KSEL;
        for (int i = 0; i < KSEL; i++) { pval[base + i] = lvals[tid][i]; pidx[base + i] = lidx[tid][i]; }
    }
}

__global__ __launch_bounds__(256) void k_merge(
        const float* __restrict__ pval, const int* __restrict__ pidx,
        const float* __restrict__ memcls,
        const float* __restrict__ cls,
        const float* __restrict__ lse, float* __restrict__ acc) {
    __shared__ float cv[4][NCHUNK * KSEL];
    __shared__ int   ci[4][NCHUNK * KSEL];
    __shared__ int   sel[4][40];
    __shared__ float blksum;
    const int w = threadIdx.x >> 6, lane = threadIdx.x & 63;
    const int row = blockIdx.x * 4 + w;
    const int NCAND = NCHUNK * KSEL;  // 164
    if (threadIdx.x == 0) blksum = 0.f;
    if (lane < 40) sel[w][lane] = 0;
#pragma unroll
    for (int s = 0; s < 3; s++) {
        int i = lane + 64 * s;
        if (i < NCAND) { cv[w][i] = pval[(size_t)row * NCAND + i]; ci[w][i] = pidx[(size_t)row * NCAND + i]; }
    }
    __syncthreads();
#pragma unroll
    for (int s = 0; s < 3; s++) {
        int i = lane + 64 * s;
        if (i < NCAND) {
            float v = cv[w][i]; int id = ci[w][i];
            int rank = 0;
            for (int t = 0; t < NCAND; t++) {
                float tv = cv[w][t]; int ti = ci[w][t];
                if (tv > v || (tv == v && ti < id)) rank++;
            }
            if (rank >= 1 && rank <= 40) sel[w][rank - 1] = id;
        }
    }
    __syncthreads();
    float sv = -INFINITY; int scls = lane;
    if (lane < NC) {
        float s2 = 0.f;
        for (int j = 0; j < 40; j++) {
            int idx = sel[w][j];
            idx = idx < 0 ? 0 : (idx > NN - 1 ? NN - 1 : idx);
            s2 += memcls[(size_t)idx * NC + lane];
        }
        sv = s2;
    }
    for (int off = 32; off; off >>= 1) {
        float ov = __shfl_xor(sv, off);
        int   oc = __shfl_xor(scls, off);
        if (ov > sv || (ov == sv && oc < scls)) { sv = ov; scls = oc; }
    }
    if (lane == 0) atomicAdd(&blksum, cls[(size_t)row * NC + scls] - lse[row]);
    __syncthreads();
    if (threadIdx.x == 0) atomicAdd(&acc[1], blksum);
}

// ======================= PATH B (tiny ws: 192 B) =======================
// M=32 rows/block, full N sweep, on-the-fly mem norms, in-kernel epilogue.

__global__ __launch_bounds__(256) void k_gemm_topk1(
        const float* __restrict__ feat,
        const float* __restrict__ mem,
        const float* __restrict__ cls,
        const float* __restrict__ memcls,
        float* __restrict__ acc) {
    __shared__ __align__(16) unsigned short Bbuf[32][520];
    __shared__ float simbuf[32][33];
    __shared__ float lvals[32][KSEL];
    __shared__ int   lidx[32][KSEL];
    __shared__ float invs[32];
    __shared__ float nrm8[32][8];
    __shared__ int   sel[4][40];
    __shared__ float blksum;

    const int tid  = threadIdx.x;
    const int lane = tid & 63;
    const int w    = tid >> 6;
    const int quad = lane >> 4;
    const int l16  = lane & 15;
    const int rowhalf = w & 1, colhalf = w >> 1;
    const int mbase = blockIdx.x * 32;

    short8 afrag[16];
    {
        const float* ar = feat + (size_t)(mbase + rowhalf * 16 + l16) * NHID + quad * 8;
#pragma unroll
        for (int s = 0; s < 16; s++) {
            float4 a = *(const float4*)(ar + s * 32);
            float4 b = *(const float4*)(ar + s * 32 + 4);
            short8 f;
            f[0] = f2b(a.x); f[1] = f2b(a.y); f[2] = f2b(a.z); f[3] = f2b(a.w);
            f[4] = f2b(b.x); f[5] = f2b(b.y); f[6] = f2b(b.z); f[7] = f2b(b.w);
            afrag[s] = f;
        }
    }

    if (tid < 32) {
        for (int i = 0; i < KSEL; i++) { lvals[tid][i] = -INFINITY; lidx[tid][i] = 0x7fffffff; }
    }
    if (tid == 0) blksum = 0.f;
    if (lane < 40) sel[w][lane] = 0;
    const bool owner = ((tid >> 3) & 7) == 0;           // 8 owners per wave
    const int  orow  = (tid >> 6) * 8 + (tid & 7);
    float minv = -INFINITY; int mini = 0x7fffffff; int minp = 0;

    for (int t = 0; t < NTILES1; t++) {
        __syncthreads();                                 // (a) prev scan done
        const int rbase = t * 32;
        float nsq = 0.f;
        int srl = 0, sp = 0;
#pragma unroll
        for (int s = 0; s < 8; s++) {
            int id = tid + s * 256;
            int rl = id >> 6, ck = id & 63;
            int rg = rbase + rl; if (rg > NN - 1) rg = NN - 1;
            const float* src = mem + (size_t)rg * NHID + ck * 8;
            float4 a = *(const float4*)src;
            float4 b = *(const float4*)(src + 4);
            short8 f;
            f[0] = f2b(a.x); f[1] = f2b(a.y); f[2] = f2b(a.z); f[3] = f2b(a.w);
            f[4] = f2b(b.x); f[5] = f2b(b.y); f[6] = f2b(b.z); f[7] = f2b(b.w);
            *(short8*)&Bbuf[rl][ck * 8] = f;
            (void)srl; (void)sp;
        }
        __syncthreads();                                 // (b) Bbuf ready
        {   // f32-exact row-norm partials: 8 threads/row x 64 elems from global
            int r = tid >> 3, p = tid & 7;
            int rg = rbase + r; if (rg > NN - 1) rg = NN - 1;
            const float* bp = mem + (size_t)rg * NHID + p * 64;
            float s = 0.f;
#pragma unroll
            for (int j = 0; j < 16; j++) {
                float4 v = *(const float4*)(bp + j * 4);
                s += v.x * v.x + v.y * v.y + v.z * v.z + v.w * v.w;
            }
            nrm8[r][p] = s;
        }
        nsq = 0.f;
        __syncthreads();                                 // (c) nrm8 ready
        if (tid < 32) {
            float s = 0.f;
#pragma unroll
            for (int p = 0; p < 8; p++) s += nrm8[tid][p];
            invs[tid] = 1.f / fmaxf(sqrtf(s), 1e-12f);
        }
        (void)nsq;
        floatx4 c4 = {0.f, 0.f, 0.f, 0.f};
#pragma unroll
        for (int s = 0; s < 16; s++) {
            short8 b = *(const short8*)&Bbuf[colhalf * 16 + l16][s * 32 + quad * 8];
            c4 = __builtin_amdgcn_mfma_f32_16x16x32_bf16(afrag[s], b, c4, 0, 0, 0);
        }
#pragma unroll
        for (int r = 0; r < 4; r++)
            simbuf[rowhalf * 16 + quad * 4 + r][colhalf * 16 + l16] = c4[r];
        __syncthreads();                                 // (d) simbuf + invs ready

        if (owner) {
            int lim = NN - rbase; if (lim > 32) lim = 32;
            for (int c = 0; c < lim; c++) {
                float v = simbuf[orow][c] * invs[c];
                if (v > minv) {
                    lvals[orow][minp] = v; lidx[orow][minp] = rbase + c;
                    minv = INFINITY; mini = -1;
                    for (int i = 0; i < KSEL; i++) {
                        float lv = lvals[orow][i]; int li = lidx[orow][i];
                        if (lv < minv || (lv == minv && li > mini)) { minv = lv; mini = li; minp = i; }
                    }
                }
            }
        }
    }
    __syncthreads();                                     // (e) all scans done

    for (int it = 0; it < 8; it++) {
        const int r32 = it * 4 + w;
        const int grow = mbase + r32;
        if (lane < KSEL) {
            float v = lvals[r32][lane]; int id = lidx[r32][lane];
            int rank = 0;
            for (int j = 0; j < KSEL; j++) {
                float tv = lvals[r32][j]; int ti = lidx[r32][j];
                if (tv > v || (tv == v && ti < id)) rank++;
            }
            if (rank >= 1 && rank <= 40) sel[w][rank - 1] = id;
        }
        __syncthreads();
        float sv = -INFINITY; int scls = lane;
        if (lane < NC) {
            float s = 0.f;
            for (int j = 0; j < 40; j++) {
                int idx = sel[w][j];
                idx = idx < 0 ? 0 : (idx > NN - 1 ? NN - 1 : idx);
                s += memcls[(size_t)idx * NC + lane];
            }
            sv = s;
        }
        for (int off = 32; off; off >>= 1) {
            float ov = __shfl_xor(sv, off);
            int   oc = __shfl_xor(scls, off);
            if (ov > sv || (ov == sv && oc < scls)) { sv = ov; scls = oc; }
        }
        float x = (lane < NC) ? cls[(size_t)grow * NC + lane] : -INFINITY;
        float mx = x;
        for (int off = 32; off; off >>= 1) mx = fmaxf(mx, __shfl_xor(mx, off));
        float e = (lane < NC) ? expf(x - mx) : 0.f;
        float S = e;
        for (int off = 32; off; off >>= 1) S += __shfl_xor(S, off);
        float lse = mx + logf(S);
        float xp = __shfl(x, scls);
        if (lane == 0) atomicAdd(&blksum, xp - lse);
        __syncthreads();
    }
    if (tid == 0) atomicAdd(&acc[1], blksum);
}

extern "C" void kernel_launch(void* const* d_in, const int* in_sizes, int n_in,
                              void* d_out, int out_size, void* d_ws, size_t ws_size,
                              hipStream_t stream) {
    const float* feat = (const float*)d_in[0];  // 8192x512  f32
    const float* cls  = (const float*)d_in[1];  // 8192x40   f32
    const float* mem  = (const float*)d_in[2];  // 50000x512 f32
    const float* mcls = (const float*)d_in[3];  // 50000x40  f32
    float* out = (float*)d_out;
    char* ws = (char*)d_ws;

    if (ws_size >= (size_t)WS_NEED) {
        float* invn = (float*)(ws + OFF_INVN);
        float* lse  = (float*)(ws + OFF_LSE);
        float* pval = (float*)(ws + OFF_PVAL);
        int*   pidx = (int*)(ws + OFF_PIDX);
        float* acc  = (float*)(ws + OFF_ACC);
        k_init<<<1, 64, 0, stream>>>(acc);
        k_cls<<<NB / 256, 256, 0, stream>>>(cls, lse, acc);
        k_invnorm<<<NN / 4, 256, 0, stream>>>(mem, invn);
        k_gemm_topk4<<<dim3(NB / 64, NCHUNK), 256, 0, stream>>>(feat, mem, invn, pval, pidx);
        k_merge<<<NB / 4, 256, 0, stream>>>(pval, pidx, mcls, cls, lse, acc);
        k_final<<<1, 64, 0, stream>>>(acc, out);
    } else {
        float* acc = (float*)ws;
        k_init<<<1, 64, 0, stream>>>(acc);
        k_cls<<<NB / 256, 256, 0, stream>>>(cls, nullptr, acc);
        k_gemm_topk1<<<NB / 32, 256, 0, stream>>>(feat, mem, cls, mcls, acc);
        k_final<<<1, 64, 0, stream>>>(acc, out);
    }
}

// Round 4
// 8820.978 us; speedup vs baseline: 1.4447x; 1.4447x over previous
//
#include <hip/hip_runtime.h>
#include <hip/hip_bf16.h>

#define NB      8192
#define NHID    512
#define NN      50000
#define NC      40
#define KSEL    41        // K+1
#define NCHUNK  4
#define CHUNK   12500
#define NTILES4 391       // ceil(12500/32)
#define NTILES1 1563      // ceil(50000/32)
#define EPS_F   1e-5f

typedef __attribute__((ext_vector_type(8))) short  short8;
typedef __attribute__((ext_vector_type(4))) float  floatx4;

// ---- big-ws layout (path A), byte offsets ----
#define OFF_INVN 0u          // 50000 f32
#define OFF_LSE  200704u     // 8192 f32
#define OFF_PVAL 233472u     // 8192*4*41 f32
#define OFF_PIDX 5607424u    // 8192*4*41 i32
#define OFF_ACC  10981376u   // [0]=entropy sum, [1]=logp sum, [2..41]=class sums
#define WS_NEED  10981568u

// f32 -> bf16 RNE scalar
__device__ __forceinline__ short f2b(float f) {
    union { float f; unsigned u; } x; x.f = f;
    unsigned r = x.u + 0x7fffu + ((x.u >> 16) & 1u);
    return (short)(r >> 16);
}
// packed f32x2 -> bf16x2 RNE (v_cvt_pk_bf16_f32)
__device__ __forceinline__ unsigned pkbf(float x, float y) {
    union { __hip_bfloat162 b; unsigned u; } c;
    c.b = __float22bfloat162_rn(make_float2(x, y));
    return c.u;
}

// full-wave argmin butterfly: (min val, tie: max idx, tie: min lane) -> uniform
__device__ __forceinline__ void argmin3(float& mv, int& mi, int& ml) {
#pragma unroll
    for (int off = 32; off; off >>= 1) {
        float ov = __shfl_xor(mv, off);
        int   oi = __shfl_xor(mi, off);
        int   ol = __shfl_xor(ml, off);
        if (ov < mv || (ov == mv && (oi > mi || (oi == mi && ol < ml)))) {
            mv = ov; mi = oi; ml = ol;
        }
    }
}

__global__ void k_init(float* __restrict__ acc) {
    int t = threadIdx.x;
    if (t < 48) acc[t] = 0.f;
}

// softmax stats on cls (f32): entropy terms, per-class sums, optional per-row lse
__global__ __launch_bounds__(256) void k_cls(const float* __restrict__ cls,
                                             float* __restrict__ lse,
                                             float* __restrict__ acc) {
    __shared__ float cacc[NC];
    __shared__ float entacc;
    int t = threadIdx.x;
    if (t == 0) entacc = 0.f;
    if (t < NC) cacc[t] = 0.f;
    __syncthreads();
    int row = blockIdx.x * 256 + t;
    float x[NC];
#pragma unroll
    for (int c = 0; c < NC; c++) x[c] = cls[row * NC + c];
    float m = x[0];
#pragma unroll
    for (int c = 1; c < NC; c++) m = fmaxf(m, x[c]);
    float S = 0.f;
#pragma unroll
    for (int c = 0; c < NC; c++) { float e = expf(x[c] - m); x[c] = e; S += e; }
    if (lse) lse[row] = m + logf(S);
    float inv = 1.f / S, ent = 0.f;
#pragma unroll
    for (int c = 0; c < NC; c++) {
        float p = x[c] * inv;
        ent += p * logf(p + EPS_F);
        atomicAdd(&cacc[c], p);
    }
    for (int off = 32; off; off >>= 1) ent += __shfl_xor(ent, off);
    if ((t & 63) == 0) atomicAdd(&entacc, ent);
    __syncthreads();
    if (t == 0) atomicAdd(&acc[0], entacc);
    if (t < NC) atomicAdd(&acc[2 + t], cacc[t]);
}

__global__ void k_final(const float* __restrict__ acc, float* __restrict__ out) {
    if (threadIdx.x == 0) {
        float ent = -acc[0] / (float)NB;
        float cl  = -acc[1] / (float)NB;
        float div = 0.f;
        for (int c = 0; c < NC; c++) {
            float msm = acc[2 + c] / (float)NB;
            div += msm * logf(msm + EPS_F);
        }
        out[0] = ent + div + cl;
    }
}

// ======================= PATH A (ws >= 11MB) =======================

__global__ __launch_bounds__(256) void k_invnorm(const float* __restrict__ mem,
                                                 float* __restrict__ invn) {
    int w = threadIdx.x >> 6, lane = threadIdx.x & 63;
    int row = blockIdx.x * 4 + w;
    const float* p = mem + (size_t)row * NHID + lane * 8;
    float4 a = *(const float4*)p;
    float4 b = *(const float4*)(p + 4);
    float s = a.x * a.x + a.y * a.y + a.z * a.z + a.w * a.w
            + b.x * b.x + b.y * b.y + b.z * b.z + b.w * b.w;
    for (int off = 32; off; off >>= 1) s += __shfl_xor(s, off);
    if (lane == 0) invn[row] = 1.f / fmaxf(sqrtf(s), 1e-12f);
}

// GEMM (f32 in, bf16 MFMA) + wave-parallel register-resident top-41.
// Block: 256 thr (4 waves), M=64 rows, N-tile=32, K=512.
// Wave w owns rows w*16..w*16+15: computes their sims AND maintains their
// top-41 lists distributed across lanes (lane j = slot j, j<41).
__global__ __launch_bounds__(256, 2) void k_gemm_topk4(
        const float* __restrict__ feat,
        const float* __restrict__ mem,
        const float* __restrict__ invn,
        float* __restrict__ pval, int* __restrict__ pidx) {
    __shared__ __align__(16) unsigned short Bbuf[32][520];
    __shared__ float simbuf[64][33];
    __shared__ float invs[32];

    const int tid  = threadIdx.x;
    const int lane = tid & 63;
    const int w    = tid >> 6;
    const int quad = lane >> 4;
    const int l16  = lane & 15;
    const int mbase  = blockIdx.x * 64;
    const int chunk  = blockIdx.y;
    const int nstart = chunk * CHUNK;

    // A fragments: row = mbase + w*16 + l16, k = s*32 + quad*8 .. +8
    short8 afrag[16];
    {
        const float* ar = feat + (size_t)(mbase + w * 16 + l16) * NHID + quad * 8;
#pragma unroll
        for (int s = 0; s < 16; s++) {
            float4 a = *(const float4*)(ar + s * 32);
            float4 b = *(const float4*)(ar + s * 32 + 4);
            union { unsigned u[4]; short8 s8; } fa;
            fa.u[0] = pkbf(a.x, a.y); fa.u[1] = pkbf(a.z, a.w);
            fa.u[2] = pkbf(b.x, b.y); fa.u[3] = pkbf(b.z, b.w);
            afrag[s] = fa.s8;
        }
    }

    // register top-41 state: lane j holds slot j of each of the wave's 16 rows
    float tval[16]; int tidx[16]; float theta[16];
#pragma unroll
    for (int r = 0; r < 16; r++) {
        tval[r]  = (lane < KSEL) ? -INFINITY : INFINITY;  // lanes 41-63 never evicted
        tidx[r]  = 0x7fffffff;
        theta[r] = -INFINITY;
    }

    for (int t = 0; t < NTILES4; t++) {
        __syncthreads();                       // prev MFMA reads of Bbuf done
        const int rbase = nstart + t * 32;
        // stage B: 32 rows x 512 (f32 global -> bf16 LDS, packed convert)
#pragma unroll
        for (int s = 0; s < 8; s++) {
            int id = tid + s * 256;
            int rl = id >> 6, ck = id & 63;
            int rg = rbase + rl; if (rg > NN - 1) rg = NN - 1;
            const float* src = mem + (size_t)rg * NHID + ck * 8;
            float4 a = *(const float4*)src;
            float4 b = *(const float4*)(src + 4);
            uint4 pk;
            pk.x = pkbf(a.x, a.y); pk.y = pkbf(a.z, a.w);
            pk.z = pkbf(b.x, b.y); pk.w = pkbf(b.z, b.w);
            *(uint4*)&Bbuf[rl][ck * 8] = pk;
        }
        if (tid < 32) { int rg = rbase + tid; invs[tid] = invn[rg > NN - 1 ? NN - 1 : rg]; }
        __syncthreads();                       // Bbuf + invs ready

        floatx4 acc0 = {0.f, 0.f, 0.f, 0.f}, acc1 = {0.f, 0.f, 0.f, 0.f};
#pragma unroll
        for (int s = 0; s < 16; s++) {
            short8 b0 = *(const short8*)&Bbuf[l16][s * 32 + quad * 8];
            short8 b1 = *(const short8*)&Bbuf[16 + l16][s * 32 + quad * 8];
            acc0 = __builtin_amdgcn_mfma_f32_16x16x32_bf16(afrag[s], b0, acc0, 0, 0, 0);
            acc1 = __builtin_amdgcn_mfma_f32_16x16x32_bf16(afrag[s], b1, acc1, 0, 0, 0);
        }
        // C: col=lane&15, row=quad*4+reg — wave w writes ONLY its own 16 rows
#pragma unroll
        for (int r = 0; r < 4; r++) {
            simbuf[w * 16 + quad * 4 + r][l16]      = acc0[r];
            simbuf[w * 16 + quad * 4 + r][16 + l16] = acc1[r];
        }
        // NO barrier: scan reads only this wave's own simbuf rows

        int lim = CHUNK - t * 32; if (lim > 32) lim = 32;
        float inv_l = (lane < 32) ? invs[lane] : 0.f;
#pragma unroll
        for (int r = 0; r < 16; r++) {
            float v = -INFINITY;
            if (lane < lim) v = simbuf[w * 16 + r][lane] * inv_l;
            if (t == 0) {                       // pre-fill slots 0-31
                if (lane < 32) { tval[r] = v; tidx[r] = rbase + lane; }
                continue;
            }
            unsigned long long m = __ballot(v > theta[r]);
            while (m) {
                int c = __ffsll((long long)m) - 1; m &= m - 1;
                float cv = __shfl(v, c);
                if (cv > theta[r]) {            // re-gate after theta updates
                    float mv = tval[r]; int mi = tidx[r]; int ml = lane;
                    argmin3(mv, mi, ml);        // evict (min val, max idx)
                    if (lane == ml) { tval[r] = cv; tidx[r] = rbase + c; }
                    float nv = tval[r]; int ni = tidx[r]; int nl = lane;
                    argmin3(nv, ni, nl);        // new threshold
                    theta[r] = nv;
                }
            }
        }
    }

    // write out: lane j<41 writes slot j of each owned row
    const int g0 = mbase + w * 16;
#pragma unroll
    for (int r = 0; r < 16; r++) {
        if (lane < KSEL) {
            int base = ((g0 + r) * NCHUNK + chunk) * KSEL;
            pval[base + lane] = tval[r];
            pidx[base + lane] = tidx[r];
        }
    }
}

__global__ __launch_bounds__(256) void k_merge(
        const float* __restrict__ pval, const int* __restrict__ pidx,
        const float* __restrict__ memcls,
        const float* __restrict__ cls,
        const float* __restrict__ lse, float* __restrict__ acc) {
    __shared__ float cv[4][NCHUNK * KSEL];
    __shared__ int   ci[4][NCHUNK * KSEL];
    __shared__ int   sel[4][40];
    __shared__ float blksum;
    const int w = threadIdx.x >> 6, lane = threadIdx.x & 63;
    const int row = blockIdx.x * 4 + w;
    const int NCAND = NCHUNK * KSEL;  // 164
    if (threadIdx.x == 0) blksum = 0.f;
    if (lane < 40) sel[w][lane] = 0;
#pragma unroll
    for (int s = 0; s < 3; s++) {
        int i = lane + 64 * s;
        if (i < NCAND) { cv[w][i] = pval[(size_t)row * NCAND + i]; ci[w][i] = pidx[(size_t)row * NCAND + i]; }
    }
    __syncthreads();
#pragma unroll
    for (int s = 0; s < 3; s++) {
        int i = lane + 64 * s;
        if (i < NCAND) {
            float v = cv[w][i]; int id = ci[w][i];
            int rank = 0;
            for (int t = 0; t < NCAND; t++) {
                float tv = cv[w][t]; int ti = ci[w][t];
                if (tv > v || (tv == v && ti < id)) rank++;
            }
            if (rank >= 1 && rank <= 40) sel[w][rank - 1] = id;
        }
    }
    __syncthreads();
    float sv = -INFINITY; int scls = lane;
    if (lane < NC) {
        float s2 = 0.f;
        for (int j = 0; j < 40; j++) {
            int idx = sel[w][j];
            idx = idx < 0 ? 0 : (idx > NN - 1 ? NN - 1 : idx);
            s2 += memcls[(size_t)idx * NC + lane];
        }
        sv = s2;
    }
    for (int off = 32; off; off >>= 1) {
        float ov = __shfl_xor(sv, off);
        int   oc = __shfl_xor(scls, off);
        if (ov > sv || (ov == sv && oc < scls)) { sv = ov; scls = oc; }
    }
    if (lane == 0) atomicAdd(&blksum, cls[(size_t)row * NC + scls] - lse[row]);
    __syncthreads();
    if (threadIdx.x == 0) atomicAdd(&acc[1], blksum);
}

// ======================= PATH B (tiny ws: 192 B) =======================
// Fallback, correctness-first (doesn't run when ws >= 11MB).

__global__ __launch_bounds__(256) void k_gemm_topk1(
        const float* __restrict__ feat,
        const float* __restrict__ mem,
        const float* __restrict__ cls,
        const float* __restrict__ memcls,
        float* __restrict__ acc) {
    __shared__ __align__(16) unsigned short Bbuf[32][520];
    __shared__ float simbuf[32][33];
    __shared__ float lvals[32][KSEL];
    __shared__ int   lidx[32][KSEL];
    __shared__ float invs[32];
    __shared__ float nrm8[32][8];
    __shared__ int   sel[4][40];
    __shared__ float blksum;

    const int tid  = threadIdx.x;
    const int lane = tid & 63;
    const int w    = tid >> 6;
    const int quad = lane >> 4;
    const int l16  = lane & 15;
    const int rowhalf = w & 1, colhalf = w >> 1;
    const int mbase = blockIdx.x * 32;

    short8 afrag[16];
    {
        const float* ar = feat + (size_t)(mbase + rowhalf * 16 + l16) * NHID + quad * 8;
#pragma unroll
        for (int s = 0; s < 16; s++) {
            float4 a = *(const float4*)(ar + s * 32);
            float4 b = *(const float4*)(ar + s * 32 + 4);
            union { unsigned u[4]; short8 s8; } fa;
            fa.u[0] = pkbf(a.x, a.y); fa.u[1] = pkbf(a.z, a.w);
            fa.u[2] = pkbf(b.x, b.y); fa.u[3] = pkbf(b.z, b.w);
            afrag[s] = fa.s8;
        }
    }

    if (tid < 32) {
        for (int i = 0; i < KSEL; i++) { lvals[tid][i] = -INFINITY; lidx[tid][i] = 0x7fffffff; }
    }
    if (tid == 0) blksum = 0.f;
    if (lane < 40) sel[w][lane] = 0;
    const bool owner = ((tid >> 3) & 7) == 0;
    const int  orow  = (tid >> 6) * 8 + (tid & 7);
    float minv = -INFINITY; int mini = 0x7fffffff; int minp = 0;

    for (int t = 0; t < NTILES1; t++) {
        __syncthreads();
        const int rbase = t * 32;
#pragma unroll
        for (int s = 0; s < 8; s++) {
            int id = tid + s * 256;
            int rl = id >> 6, ck = id & 63;
            int rg = rbase + rl; if (rg > NN - 1) rg = NN - 1;
            const float* src = mem + (size_t)rg * NHID + ck * 8;
            float4 a = *(const float4*)src;
            float4 b = *(const float4*)(src + 4);
            uint4 pk;
            pk.x = pkbf(a.x, a.y); pk.y = pkbf(a.z, a.w);
            pk.z = pkbf(b.x, b.y); pk.w = pkbf(b.z, b.w);
            *(uint4*)&Bbuf[rl][ck * 8] = pk;
        }
        __syncthreads();
        {
            int r = tid >> 3, p = tid & 7;
            int rg = rbase + r; if (rg > NN - 1) rg = NN - 1;
            const float* bp = mem + (size_t)rg * NHID + p * 64;
            float s = 0.f;
#pragma unroll
            for (int j = 0; j < 16; j++) {
                float4 v = *(const float4*)(bp + j * 4);
                s += v.x * v.x + v.y * v.y + v.z * v.z + v.w * v.w;
            }
            nrm8[r][p] = s;
        }
        __syncthreads();
        if (tid < 32) {
            float s = 0.f;
#pragma unroll
            for (int p = 0; p < 8; p++) s += nrm8[tid][p];
            invs[tid] = 1.f / fmaxf(sqrtf(s), 1e-12f);
        }
        floatx4 c4 = {0.f, 0.f, 0.f, 0.f};
#pragma unroll
        for (int s = 0; s < 16; s++) {
            short8 b = *(const short8*)&Bbuf[colhalf * 16 + l16][s * 32 + quad * 8];
            c4 = __builtin_amdgcn_mfma_f32_16x16x32_bf16(afrag[s], b, c4, 0, 0, 0);
        }
#pragma unroll
        for (int r = 0; r < 4; r++)
            simbuf[rowhalf * 16 + quad * 4 + r][colhalf * 16 + l16] = c4[r];
        __syncthreads();

        if (owner) {
            int lim = NN - rbase; if (lim > 32) lim = 32;
            for (int c = 0; c < lim; c++) {
                float v = simbuf[orow][c] * invs[c];
                if (v > minv) {
                    lvals[orow][minp] = v; lidx[orow][minp] = rbase + c;
                    minv = INFINITY; mini = -1;
                    for (int i = 0; i < KSEL; i++) {
                        float lv = lvals[orow][i]; int li = lidx[orow][i];
                        if (lv < minv || (lv == minv && li > mini)) { minv = lv; mini = li; minp = i; }
                    }
                }
            }
        }
    }
    __syncthreads();

    for (int it = 0; it < 8; it++) {
        const int r32 = it * 4 + w;
        const int grow = mbase + r32;
        if (lane < KSEL) {
            float v = lvals[r32][lane]; int id = lidx[r32][lane];
            int rank = 0;
            for (int j = 0; j < KSEL; j++) {
                float tv = lvals[r32][j]; int ti = lidx[r32][j];
                if (tv > v || (tv == v && ti < id)) rank++;
            }
            if (rank >= 1 && rank <= 40) sel[w][rank - 1] = id;
        }
        __syncthreads();
        float sv = -INFINITY; int scls = lane;
        if (lane < NC) {
            float s = 0.f;
            for (int j = 0; j < 40; j++) {
                int idx = sel[w][j];
                idx = idx < 0 ? 0 : (idx > NN - 1 ? NN - 1 : idx);
                s += memcls[(size_t)idx * NC + lane];
            }
            sv = s;
        }
        for (int off = 32; off; off >>= 1) {
            float ov = __shfl_xor(sv, off);
            int   oc = __shfl_xor(scls, off);
            if (ov > sv || (ov == sv && oc < scls)) { sv = ov; scls = oc; }
        }
        float x = (lane < NC) ? cls[(size_t)grow * NC + lane] : -INFINITY;
        float mx = x;
        for (int off = 32; off; off >>= 1) mx = fmaxf(mx, __shfl_xor(mx, off));
        float e = (lane < NC) ? expf(x - mx) : 0.f;
        float S = e;
        for (int off = 32; off; off >>= 1) S += __shfl_xor(S, off);
        float lse = mx + logf(S);
        float xp = __shfl(x, scls);
        if (lane == 0) atomicAdd(&blksum, xp - lse);
        __syncthreads();
    }
    if (tid == 0) atomicAdd(&acc[1], blksum);
}

extern "C" void kernel_launch(void* const* d_in, const int* in_sizes, int n_in,
                              void* d_out, int out_size, void* d_ws, size_t ws_size,
                              hipStream_t stream) {
    const float* feat = (const float*)d_in[0];  // 8192x512  f32
    const float* cls  = (const float*)d_in[1];  // 8192x40   f32
    const float* mem  = (const float*)d_in[2];  // 50000x512 f32
    const float* mcls = (const float*)d_in[3];  // 50000x40  f32
    float* out = (float*)d_out;
    char* ws = (char*)d_ws;

    if (ws_size >= (size_t)WS_NEED) {
        float* invn = (float*)(ws + OFF_INVN);
        float* lse  = (float*)(ws + OFF_LSE);
        float* pval = (float*)(ws + OFF_PVAL);
        int*   pidx = (int*)(ws + OFF_PIDX);
        float* acc  = (float*)(ws + OFF_ACC);
        k_init<<<1, 64, 0, stream>>>(acc);
        k_cls<<<NB / 256, 256, 0, stream>>>(cls, lse, acc);
        k_invnorm<<<NN / 4, 256, 0, stream>>>(mem, invn);
        k_gemm_topk4<<<dim3(NB / 64, NCHUNK), 256, 0, stream>>>(feat, mem, invn, pval, pidx);
        k_merge<<<NB / 4, 256, 0, stream>>>(pval, pidx, mcls, cls, lse, acc);
        k_final<<<1, 64, 0, stream>>>(acc, out);
    } else {
        float* acc = (float*)ws;
        k_init<<<1, 64, 0, stream>>>(acc);
        k_cls<<<NB / 256, 256, 0, stream>>>(cls, nullptr, acc);
        k_gemm_topk1<<<NB / 32, 256, 0, stream>>>(feat, mem, cls, mcls, acc);
        k_final<<<1, 64, 0, stream>>>(acc, out);
    }
}

// Round 5
// 2914.626 us; speedup vs baseline: 4.3722x; 3.0265x over previous
//
#include <hip/hip_runtime.h>
#include <hip/hip_bf16.h>

#define NB      8192
#define NHID    512
#define NN      50000
#define NC      40
#define KSEL    41        // K+1
#define NCHUNK  4
#define CHUNK   12500
#define NTILES4 391       // ceil(12500/32)
#define NTILES1 1563      // ceil(50000/32)
#define EPS_F   1e-5f
#define BCAP    56        // candidate buffer entries per row
#define BTRIG   24        // compact when cnt > BTRIG (24+32 <= 56)

typedef __attribute__((ext_vector_type(8))) short  short8;
typedef __attribute__((ext_vector_type(4))) float  floatx4;

// ---- ws layout, byte offsets ----
#define OFF_INVN 0u          // 50000 f32
#define OFF_LSE  200704u     // 8192 f32
#define OFF_PVAL 233472u     // 8192*4*41 f32
#define OFF_PIDX 5607424u    // 8192*4*41 i32
#define OFF_ACC  10981376u   // 48 f32
#define WS_NEED  10981568u
#define OFF_MEMB 10981632u   // 50000*512 bf16 = 51.2MB (optional)
#define WS_BF16_NEED (10981632u + 51200000u)

// packed f32x2 -> bf16x2 RNE (v_cvt_pk_bf16_f32)
__device__ __forceinline__ unsigned pkbf(float x, float y) {
    union { __hip_bfloat162 b; unsigned u; } c;
    c.b = __float22bfloat162_rn(make_float2(x, y));
    return c.u;
}
// total order: value desc, index asc (jax.lax.top_k tie semantics)
__device__ __forceinline__ int simgt(float av, int ai, float bv, int bi) {
    return (av > bv || (av == bv && ai < bi)) ? 1 : 0;
}

__global__ void k_init(float* __restrict__ acc) {
    int t = threadIdx.x;
    if (t < 48) acc[t] = 0.f;
}

// softmax stats on cls: entropy terms, per-class sums, optional per-row lse
__global__ __launch_bounds__(256) void k_cls(const float* __restrict__ cls,
                                             float* __restrict__ lse,
                                             float* __restrict__ acc) {
    __shared__ float cacc[NC];
    __shared__ float entacc;
    int t = threadIdx.x;
    if (t == 0) entacc = 0.f;
    if (t < NC) cacc[t] = 0.f;
    __syncthreads();
    int row = blockIdx.x * 256 + t;
    float x[NC];
#pragma unroll
    for (int c = 0; c < NC; c++) x[c] = cls[row * NC + c];
    float m = x[0];
#pragma unroll
    for (int c = 1; c < NC; c++) m = fmaxf(m, x[c]);
    float S = 0.f;
#pragma unroll
    for (int c = 0; c < NC; c++) { float e = expf(x[c] - m); x[c] = e; S += e; }
    if (lse) lse[row] = m + logf(S);
    float inv = 1.f / S, ent = 0.f;
#pragma unroll
    for (int c = 0; c < NC; c++) {
        float p = x[c] * inv;
        ent += p * logf(p + EPS_F);
        atomicAdd(&cacc[c], p);
    }
    for (int off = 32; off; off >>= 1) ent += __shfl_xor(ent, off);
    if ((t & 63) == 0) atomicAdd(&entacc, ent);
    __syncthreads();
    if (t == 0) atomicAdd(&acc[0], entacc);
    if (t < NC) atomicAdd(&acc[2 + t], cacc[t]);
}

__global__ void k_final(const float* __restrict__ acc, float* __restrict__ out) {
    if (threadIdx.x == 0) {
        float ent = -acc[0] / (float)NB;
        float cl  = -acc[1] / (float)NB;
        float div = 0.f;
        for (int c = 0; c < NC; c++) {
            float msm = acc[2 + c] / (float)NB;
            div += msm * logf(msm + EPS_F);
        }
        out[0] = ent + div + cl;
    }
}

// ======================= PATH A (ws >= 11MB) =======================

__global__ __launch_bounds__(256) void k_invnorm(const float* __restrict__ mem,
                                                 float* __restrict__ invn) {
    int w = threadIdx.x >> 6, lane = threadIdx.x & 63;
    int row = blockIdx.x * 4 + w;
    const float* p = mem + (size_t)row * NHID + lane * 8;
    float4 a = *(const float4*)p;
    float4 b = *(const float4*)(p + 4);
    float s = a.x * a.x + a.y * a.y + a.z * a.z + a.w * a.w
            + b.x * b.x + b.y * b.y + b.z * b.z + b.w * b.w;
    for (int off = 32; off; off >>= 1) s += __shfl_xor(s, off);
    if (lane == 0) invn[row] = 1.f / fmaxf(sqrtf(s), 1e-12f);
}

// one-time f32 -> bf16 conversion of mem into ws (only if ws is big enough)
__global__ __launch_bounds__(256) void k_memcvt(const float* __restrict__ mem,
                                                unsigned short* __restrict__ memb) {
    size_t base = ((size_t)blockIdx.x * 256 + threadIdx.x) * 16;
    const float* s = mem + base;
    float4 a = *(const float4*)s;
    float4 b = *(const float4*)(s + 4);
    float4 c = *(const float4*)(s + 8);
    float4 d = *(const float4*)(s + 12);
    uint4 p0, p1;
    p0.x = pkbf(a.x, a.y); p0.y = pkbf(a.z, a.w);
    p0.z = pkbf(b.x, b.y); p0.w = pkbf(b.z, b.w);
    p1.x = pkbf(c.x, c.y); p1.y = pkbf(c.z, c.w);
    p1.z = pkbf(d.x, d.y); p1.w = pkbf(d.z, d.w);
    *(uint4*)(memb + base)     = p0;
    *(uint4*)(memb + base + 8) = p1;
}

// GEMM (bf16 MFMA) + buffered exact top-41: ballot-append candidates to a
// per-row LDS buffer, batch-compact (wave-parallel rank counting) when full.
template <bool BF16WS>
__global__ __launch_bounds__(256, 2) void k_gemm_topk4(
        const float* __restrict__ feat,
        const float* __restrict__ mem,
        const unsigned short* __restrict__ memb,
        const float* __restrict__ invn,
        float* __restrict__ pval, int* __restrict__ pidx) {
    __shared__ __align__(16) unsigned short Bbuf[32][520];
    __shared__ float simbuf[64][33];
    __shared__ float invs[32];
    __shared__ float bufval[64][BCAP];
    __shared__ unsigned short bufidx[64][BCAP];   // chunk-relative (<12500)
    __shared__ float swv[4][KSEL];
    __shared__ int   swi[4][KSEL];

    const int tid  = threadIdx.x;
    const int lane = tid & 63;
    const int w    = tid >> 6;
    const int quad = lane >> 4;
    const int l16  = lane & 15;
    const int col  = lane & 31;
    const int half = lane >> 5;
    const int mbase  = blockIdx.x * 64;
    const int chunk  = blockIdx.y;
    const int nstart = chunk * CHUNK;

    // A fragments: row = mbase + w*16 + l16, k = s*32 + quad*8 .. +8
    short8 afrag[16];
    {
        const float* ar = feat + (size_t)(mbase + w * 16 + l16) * NHID + quad * 8;
#pragma unroll
        for (int s = 0; s < 16; s++) {
            float4 a = *(const float4*)(ar + s * 32);
            float4 b = *(const float4*)(ar + s * 32 + 4);
            union { unsigned u[4]; short8 s8; } fa;
            fa.u[0] = pkbf(a.x, a.y); fa.u[1] = pkbf(a.z, a.w);
            fa.u[2] = pkbf(b.x, b.y); fa.u[3] = pkbf(b.z, b.w);
            afrag[s] = fa.s8;
        }
    }

    // register top-41: lane j<41 holds slot j of each of the wave's 16 rows
    float tval[16]; int tidx[16]; float theta[16]; int cnt[16];
#pragma unroll
    for (int r = 0; r < 16; r++) {
        tval[r] = -INFINITY; tidx[r] = 0x7fffffff; theta[r] = -INFINITY; cnt[r] = 0;
    }

    // wave-parallel exact compaction of row R: top-41 of (41 regs + cnt buffered)
    auto compact = [&](int R, float& tv, int& ti, float& th, int& c) {
        if (lane < KSEL) { swv[w][lane] = -INFINITY; swi[w][lane] = 0x7fffffff; }
        float v0 = -INFINITY; int i0 = 0x7fffffff;
        if (lane < c) { v0 = bufval[R][lane]; i0 = nstart + (int)bufidx[R][lane]; }
        int rr_ = 0, r0 = 0;
        for (int t2 = 0; t2 < c; t2++) {                 // buffered, LDS broadcast
            float bv = bufval[R][t2];
            int   bi = nstart + (int)bufidx[R][t2];
            rr_ += simgt(bv, bi, tv, ti);
            r0  += simgt(bv, bi, v0, i0);
        }
#pragma unroll
        for (int t2 = 0; t2 < KSEL; t2++) {              // regs, readlane broadcast
            float bv = __shfl(tv, t2);
            int   bi = __shfl(ti, t2);
            rr_ += simgt(bv, bi, tv, ti);
            r0  += simgt(bv, bi, v0, i0);
        }
        asm volatile("s_waitcnt lgkmcnt(0)" ::: "memory");
        if (rr_ < KSEL)              { swv[w][rr_] = tv; swi[w][rr_] = ti; }
        if (r0  < KSEL && lane < c)  { swv[w][r0]  = v0; swi[w][r0]  = i0; }
        asm volatile("s_waitcnt lgkmcnt(0)" ::: "memory");
        float nv = -INFINITY; int ni = 0x7fffffff;
        if (lane < KSEL) { nv = swv[w][lane]; ni = swi[w][lane]; }
        tv = nv; ti = ni;
        th = swv[w][KSEL - 1];
        c = 0;
    };

    for (int t = 0; t < NTILES4; t++) {
        __syncthreads();                       // prev tile's Bbuf reads done
        const int rbase = nstart + t * 32;
#pragma unroll
        for (int s = 0; s < 8; s++) {
            int id = tid + s * 256;
            int rl = id >> 6, ck = id & 63;
            int rg = rbase + rl; if (rg > NN - 1) rg = NN - 1;
            if (BF16WS) {
                *(uint4*)&Bbuf[rl][ck * 8] = *(const uint4*)(memb + (size_t)rg * NHID + ck * 8);
            } else {
                const float* src = mem + (size_t)rg * NHID + ck * 8;
                float4 a = *(const float4*)src;
                float4 b = *(const float4*)(src + 4);
                uint4 pk;
                pk.x = pkbf(a.x, a.y); pk.y = pkbf(a.z, a.w);
                pk.z = pkbf(b.x, b.y); pk.w = pkbf(b.z, b.w);
                *(uint4*)&Bbuf[rl][ck * 8] = pk;
            }
        }
        if (tid < 32) { int rg = rbase + tid; invs[tid] = invn[rg > NN - 1 ? NN - 1 : rg]; }
        __syncthreads();                       // Bbuf + invs ready

        floatx4 acc0 = {0.f, 0.f, 0.f, 0.f}, acc1 = {0.f, 0.f, 0.f, 0.f};
#pragma unroll
        for (int s = 0; s < 16; s++) {
            short8 b0 = *(const short8*)&Bbuf[l16][s * 32 + quad * 8];
            short8 b1 = *(const short8*)&Bbuf[16 + l16][s * 32 + quad * 8];
            acc0 = __builtin_amdgcn_mfma_f32_16x16x32_bf16(afrag[s], b0, acc0, 0, 0, 0);
            acc1 = __builtin_amdgcn_mfma_f32_16x16x32_bf16(afrag[s], b1, acc1, 0, 0, 0);
        }
        // C: col=lane&15, row=quad*4+reg — wave w writes ONLY its own 16 rows
#pragma unroll
        for (int r = 0; r < 4; r++) {
            simbuf[w * 16 + quad * 4 + r][l16]      = acc0[r];
            simbuf[w * 16 + quad * 4 + r][16 + l16] = acc1[r];
        }
        // no barrier: this wave reads only its own simbuf rows

        int lim = CHUNK - t * 32; if (lim > 32) lim = 32;
        float inv_c = invs[col];
        const int relbase = t * 32;            // chunk-relative index base
#pragma unroll
        for (int p = 0; p < 8; p++) {          // lanes 0-31: row p; 32-63: row p+8
            const int myrow = w * 16 + p + (half << 3);
            float v = -INFINITY;
            if (col < lim) v = simbuf[myrow][col] * inv_c;
            float th = half ? theta[p + 8] : theta[p];
            unsigned long long mk = __ballot(v > th);
            unsigned mlo = (unsigned)mk;
            unsigned mhi = (unsigned)(mk >> 32);
            if (mlo) {
                if (!half && ((mlo >> col) & 1u)) {
                    int pos = cnt[p] + __popc(mlo & ((1u << col) - 1u));
                    bufval[w * 16 + p][pos] = v;
                    bufidx[w * 16 + p][pos] = (unsigned short)(relbase + col);
                }
                cnt[p] += __popc(mlo);
            }
            if (mhi) {
                if (half && ((mhi >> col) & 1u)) {
                    int pos = cnt[p + 8] + __popc(mhi & ((1u << col) - 1u));
                    bufval[w * 16 + p + 8][pos] = v;
                    bufidx[w * 16 + p + 8][pos] = (unsigned short)(relbase + col);
                }
                cnt[p + 8] += __popc(mhi);
            }
            if (cnt[p] > BTRIG)
                compact(w * 16 + p, tval[p], tidx[p], theta[p], cnt[p]);
            if (cnt[p + 8] > BTRIG)
                compact(w * 16 + p + 8, tval[p + 8], tidx[p + 8], theta[p + 8], cnt[p + 8]);
        }
    }

    // flush + write out
    const int g0 = mbase + w * 16;
#pragma unroll
    for (int p = 0; p < 16; p++) {
        if (cnt[p] > 0)
            compact(w * 16 + p, tval[p], tidx[p], theta[p], cnt[p]);
        if (lane < KSEL) {
            int base = ((g0 + p) * NCHUNK + chunk) * KSEL;
            pval[base + lane] = tval[p];
            pidx[base + lane] = tidx[p];
        }
    }
}

__global__ __launch_bounds__(256) void k_merge(
        const float* __restrict__ pval, const int* __restrict__ pidx,
        const float* __restrict__ memcls,
        const float* __restrict__ cls,
        const float* __restrict__ lse, float* __restrict__ acc) {
    __shared__ float cv[4][NCHUNK * KSEL];
    __shared__ int   ci[4][NCHUNK * KSEL];
    __shared__ int   sel[4][40];
    __shared__ float blksum;
    const int w = threadIdx.x >> 6, lane = threadIdx.x & 63;
    const int row = blockIdx.x * 4 + w;
    const int NCAND = NCHUNK * KSEL;  // 164
    if (threadIdx.x == 0) blksum = 0.f;
    if (lane < 40) sel[w][lane] = 0;
#pragma unroll
    for (int s = 0; s < 3; s++) {
        int i = lane + 64 * s;
        if (i < NCAND) { cv[w][i] = pval[(size_t)row * NCAND + i]; ci[w][i] = pidx[(size_t)row * NCAND + i]; }
    }
    __syncthreads();
#pragma unroll
    for (int s = 0; s < 3; s++) {
        int i = lane + 64 * s;
        if (i < NCAND) {
            float v = cv[w][i]; int id = ci[w][i];
            int rank = 0;
            for (int t = 0; t < NCAND; t++) {
                float tv = cv[w][t]; int ti = ci[w][t];
                if (tv > v || (tv == v && ti < id)) rank++;
            }
            if (rank >= 1 && rank <= 40) sel[w][rank - 1] = id;
        }
    }
    __syncthreads();
    float sv = -INFINITY; int scls = lane;
    if (lane < NC) {
        float s2 = 0.f;
        for (int j = 0; j < 40; j++) {
            int idx = sel[w][j];
            idx = idx < 0 ? 0 : (idx > NN - 1 ? NN - 1 : idx);
            s2 += memcls[(size_t)idx * NC + lane];
        }
        sv = s2;
    }
    for (int off = 32; off; off >>= 1) {
        float ov = __shfl_xor(sv, off);
        int   oc = __shfl_xor(scls, off);
        if (ov > sv || (ov == sv && oc < scls)) { sv = ov; scls = oc; }
    }
    if (lane == 0) atomicAdd(&blksum, cls[(size_t)row * NC + scls] - lse[row]);
    __syncthreads();
    if (threadIdx.x == 0) atomicAdd(&acc[1], blksum);
}

// ======================= PATH B (tiny ws) — fallback, never runs when ws>=11MB
__global__ __launch_bounds__(256) void k_gemm_topk1(
        const float* __restrict__ feat,
        const float* __restrict__ mem,
        const float* __restrict__ cls,
        const float* __restrict__ memcls,
        float* __restrict__ acc) {
    __shared__ __align__(16) unsigned short Bbuf[32][520];
    __shared__ float simbuf[32][33];
    __shared__ float lvals[32][KSEL];
    __shared__ int   lidx[32][KSEL];
    __shared__ float invs[32];
    __shared__ float nrm8[32][8];
    __shared__ int   sel[4][40];
    __shared__ float blksum;

    const int tid  = threadIdx.x;
    const int lane = tid & 63;
    const int w    = tid >> 6;
    const int quad = lane >> 4;
    const int l16  = lane & 15;
    const int rowhalf = w & 1, colhalf = w >> 1;
    const int mbase = blockIdx.x * 32;

    short8 afrag[16];
    {
        const float* ar = feat + (size_t)(mbase + rowhalf * 16 + l16) * NHID + quad * 8;
#pragma unroll
        for (int s = 0; s < 16; s++) {
            float4 a = *(const float4*)(ar + s * 32);
            float4 b = *(const float4*)(ar + s * 32 + 4);
            union { unsigned u[4]; short8 s8; } fa;
            fa.u[0] = pkbf(a.x, a.y); fa.u[1] = pkbf(a.z, a.w);
            fa.u[2] = pkbf(b.x, b.y); fa.u[3] = pkbf(b.z, b.w);
            afrag[s] = fa.s8;
        }
    }

    if (tid < 32) {
        for (int i = 0; i < KSEL; i++) { lvals[tid][i] = -INFINITY; lidx[tid][i] = 0x7fffffff; }
    }
    if (tid == 0) blksum = 0.f;
    if (lane < 40) sel[w][lane] = 0;
    const bool owner = ((tid >> 3) & 7) == 0;
    const int  orow  = (tid >> 6) * 8 + (tid & 7);
    float minv = -INFINITY; int mini = 0x7fffffff; int minp = 0;

    for (int t = 0; t < NTILES1; t++) {
        __syncthreads();
        const int rbase = t * 32;
#pragma unroll
        for (int s = 0; s < 8; s++) {
            int id = tid + s * 256;
            int rl = id >> 6, ck = id & 63;
            int rg = rbase + rl; if (rg > NN - 1) rg = NN - 1;
            const float* src = mem + (size_t)rg * NHID + ck * 8;
            float4 a = *(const float4*)src;
            float4 b = *(const float4*)(src + 4);
            uint4 pk;
            pk.x = pkbf(a.x, a.y); pk.y = pkbf(a.z, a.w);
            pk.z = pkbf(b.x, b.y); pk.w = pkbf(b.z, b.w);
            *(uint4*)&Bbuf[rl][ck * 8] = pk;
        }
        __syncthreads();
        {
            int r = tid >> 3, p = tid & 7;
            int rg = rbase + r; if (rg > NN - 1) rg = NN - 1;
            const float* bp = mem + (size_t)rg * NHID + p * 64;
            float s = 0.f;
#pragma unroll
            for (int j = 0; j < 16; j++) {
                float4 v = *(const float4*)(bp + j * 4);
                s += v.x * v.x + v.y * v.y + v.z * v.z + v.w * v.w;
            }
            nrm8[r][p] = s;
        }
        __syncthreads();
        if (tid < 32) {
            float s = 0.f;
#pragma unroll
            for (int p = 0; p < 8; p++) s += nrm8[tid][p];
            invs[tid] = 1.f / fmaxf(sqrtf(s), 1e-12f);
        }
        floatx4 c4 = {0.f, 0.f, 0.f, 0.f};
#pragma unroll
        for (int s = 0; s < 16; s++) {
            short8 b = *(const short8*)&Bbuf[colhalf * 16 + l16][s * 32 + quad * 8];
            c4 = __builtin_amdgcn_mfma_f32_16x16x32_bf16(afrag[s], b, c4, 0, 0, 0);
        }
#pragma unroll
        for (int r = 0; r < 4; r++)
            simbuf[rowhalf * 16 + quad * 4 + r][colhalf * 16 + l16] = c4[r];
        __syncthreads();

        if (owner) {
            int lim = NN - rbase; if (lim > 32) lim = 32;
            for (int c = 0; c < lim; c++) {
                float v = simbuf[orow][c] * invs[c];
                if (v > minv) {
                    lvals[orow][minp] = v; lidx[orow][minp] = rbase + c;
                    minv = INFINITY; mini = -1;
                    for (int i = 0; i < KSEL; i++) {
                        float lv = lvals[orow][i]; int li = lidx[orow][i];
                        if (lv < minv || (lv == minv && li > mini)) { minv = lv; mini = li; minp = i; }
                    }
                }
            }
        }
    }
    __syncthreads();

    for (int it = 0; it < 8; it++) {
        const int r32 = it * 4 + w;
        const int grow = mbase + r32;
        if (lane < KSEL) {
            float v = lvals[r32][lane]; int id = lidx[r32][lane];
            int rank = 0;
            for (int j = 0; j < KSEL; j++) {
                float tv = lvals[r32][j]; int ti = lidx[r32][j];
                if (tv > v || (tv == v && ti < id)) rank++;
            }
            if (rank >= 1 && rank <= 40) sel[w][rank - 1] = id;
        }
        __syncthreads();
        float sv = -INFINITY; int scls = lane;
        if (lane < NC) {
            float s = 0.f;
            for (int j = 0; j < 40; j++) {
                int idx = sel[w][j];
                idx = idx < 0 ? 0 : (idx > NN - 1 ? NN - 1 : idx);
                s += memcls[(size_t)idx * NC + lane];
            }
            sv = s;
        }
        for (int off = 32; off; off >>= 1) {
            float ov = __shfl_xor(sv, off);
            int   oc = __shfl_xor(scls, off);
            if (ov > sv || (ov == sv && oc < scls)) { sv = ov; scls = oc; }
        }
        float x = (lane < NC) ? cls[(size_t)grow * NC + lane] : -INFINITY;
        float mx = x;
        for (int off = 32; off; off >>= 1) mx = fmaxf(mx, __shfl_xor(mx, off));
        float e = (lane < NC) ? expf(x - mx) : 0.f;
        float S = e;
        for (int off = 32; off; off >>= 1) S += __shfl_xor(S, off);
        float lse = mx + logf(S);
        float xp = __shfl(x, scls);
        if (lane == 0) atomicAdd(&blksum, xp - lse);
        __syncthreads();
    }
    if (tid == 0) atomicAdd(&acc[1], blksum);
}

extern "C" void kernel_launch(void* const* d_in, const int* in_sizes, int n_in,
                              void* d_out, int out_size, void* d_ws, size_t ws_size,
                              hipStream_t stream) {
    const float* feat = (const float*)d_in[0];  // 8192x512  f32
    const float* cls  = (const float*)d_in[1];  // 8192x40   f32
    const float* mem  = (const float*)d_in[2];  // 50000x512 f32
    const float* mcls = (const float*)d_in[3];  // 50000x40  f32
    float* out = (float*)d_out;
    char* ws = (char*)d_ws;

    if (ws_size >= (size_t)WS_NEED) {
        float* invn = (float*)(ws + OFF_INVN);
        float* lse  = (float*)(ws + OFF_LSE);
        float* pval = (float*)(ws + OFF_PVAL);
        int*   pidx = (int*)(ws + OFF_PIDX);
        float* acc  = (float*)(ws + OFF_ACC);
        k_init<<<1, 64, 0, stream>>>(acc);
        k_cls<<<NB / 256, 256, 0, stream>>>(cls, lse, acc);
        k_invnorm<<<NN / 4, 256, 0, stream>>>(mem, invn);
        if (ws_size >= (size_t)WS_BF16_NEED) {
            unsigned short* memb = (unsigned short*)(ws + OFF_MEMB);
            k_memcvt<<<(NN * NHID) / (256 * 16), 256, 0, stream>>>(mem, memb);
            k_gemm_topk4<true><<<dim3(NB / 64, NCHUNK), 256, 0, stream>>>(
                feat, mem, memb, invn, pval, pidx);
        } else {
            k_gemm_topk4<false><<<dim3(NB / 64, NCHUNK), 256, 0, stream>>>(
                feat, mem, nullptr, invn, pval, pidx);
        }
        k_merge<<<NB / 4, 256, 0, stream>>>(pval, pidx, mcls, cls, lse, acc);
        k_final<<<1, 64, 0, stream>>>(acc, out);
    } else {
        float* acc = (float*)ws;
        k_init<<<1, 64, 0, stream>>>(acc);
        k_cls<<<NB / 256, 256, 0, stream>>>(cls, nullptr, acc);
        k_gemm_topk1<<<NB / 32, 256, 0, stream>>>(feat, mem, cls, mcls, acc);
        k_final<<<1, 64, 0, stream>>>(acc, out);
    }
}